// Round 7
// baseline (21314.732 us; speedup 1.0000x reference)
//
#include <hip/hip_runtime.h>
#include <hip/hip_bf16.h>

#define S_LEN 1024
#define BATCH 128
#define HDIM  256
#define IDIM  256

// Persistent fused LSTM, round 7.
// vs round 6: 2 blocks/CU (grid 512) for latency hiding. Groups of 16 h-blocks
// (each owns 16 h-rows x 4 gates x k=256) halve per-thread weight regs to
// 32+32 so total regs fit <=128 -> 16 waves/CU. The 2 blocks on a CU are from
// DIFFERENT batch groups (independent sync) -> phases slide; one computes
// while the other waits on MALL. __launch_bounds__(512,4) pins the allocator.
// Thread tile: 1 gh-row x 32-k (acc[4]); reduce = 3 shfl stages over 8 ks-lanes.
// Rotation (ks+j)&7 spreads matvec ds_read_b128 over all 8 16B-slots ->
// conflict-free (round 6's residual 2-way pair collision removed).
// Sync protocol unchanged (proven r3-r6): relaxed agent-scope atomics
// (sc0 sc1, no cache maintenance); producer h-stores drained by the
// s_waitcnt vmcnt(0) at __syncthreads before tid0 sets its flag; consumers
// poll 16 tiny flags then bulk-read h once. Two-slot ping-pong: writer of
// slot p at t+2 gated via flags>=t+2 behind all peers' stage-reads of slot p
// at t+1 -> no overwrite hazard (group-size independent).
//
// grid = 512: bg = bid>>4 (32 batch groups x 4 rows), hsl = bid&15 (16 h-rows).
// Contiguous 16-block groups -> safe progress even under partial residency.
// block = 512 threads: tid = row*8 + ks (row 0..63 gh-row, ks 0..7 k-slice).

__global__ __launch_bounds__(512, 4) void lstm_persist(
    const float* __restrict__ x,
    const float* __restrict__ Wxi, const float* __restrict__ Whi,
    const float* __restrict__ bxi, const float* __restrict__ bhi,
    const float* __restrict__ Wxf, const float* __restrict__ Whf,
    const float* __restrict__ bxf, const float* __restrict__ bhf,
    const float* __restrict__ Wxo, const float* __restrict__ Who,
    const float* __restrict__ bxo, const float* __restrict__ bho,
    const float* __restrict__ Wxc, const float* __restrict__ Whc,
    const float* __restrict__ bxc, const float* __restrict__ bhc,
    float* __restrict__ out,            // h_seq (S,B,H) then h(B,H) then c(B,H)
    float* __restrict__ hslot,          // ws: 2 * B * H floats, zeroed
    unsigned int* __restrict__ flags)   // ws: 512 * 16 u32 (64B stride), zeroed
{
  const int bid = blockIdx.x;
  const int bg  = bid >> 4;   // 0..31 batch group (4 rows)
  const int hsl = bid & 15;   // 0..15 h-slice (16 h-rows)
  const int tid = threadIdx.x;
  const int row = tid >> 3;   // 0..63 : gh-row = gate*16 + h16
  const int ks  = tid & 7;    // 0..7  : 32-wide k-slice
  const int b0  = bg * 4;

  // rotated k-columns: 8 float4 per thread, slot 4*((ks+j)&7) -> all 32 banks
  int col8[8];
#pragma unroll
  for (int j = 0; j < 8; ++j) col8[j] = ks * 32 + 4 * ((ks + j) & 7);

  // pin weights: 1 gh-row x 32 k (rotated order): 32 Wh + 32 Wx floats
  const int g    = row >> 4;
  const int h16r = row & 15;
  const int hrow = hsl * 16 + h16r;
  const float* Whp = (g == 0) ? Whi : (g == 1) ? Whf : (g == 2) ? Who : Whc;
  const float* Wxp = (g == 0) ? Wxi : (g == 1) ? Wxf : (g == 2) ? Wxo : Wxc;
  float wh[32], wx[32];
#pragma unroll
  for (int j = 0; j < 8; ++j) {
    float4 a = *(const float4*)(Whp + (size_t)hrow * HDIM + col8[j]);
    wh[4*j+0] = a.x; wh[4*j+1] = a.y; wh[4*j+2] = a.z; wh[4*j+3] = a.w;
    float4 c = *(const float4*)(Wxp + (size_t)hrow * IDIM + col8[j]);
    wx[4*j+0] = c.x; wx[4*j+1] = c.y; wx[4*j+2] = c.z; wx[4*j+3] = c.w;
  }

  // combine identity (tid<64): cb = tid>>4 batch row, ch16 = tid&15 h-row
  const int cb   = tid >> 4;
  const int ch16 = tid & 15;
  const int chrow = hsl * 16 + ch16;
  const float bias_i = bxi[chrow] + bhi[chrow];
  const float bias_f = bxf[chrow] + bhf[chrow];
  const float bias_o = bxo[chrow] + bho[chrow];
  const float bias_c = bxc[chrow] + bhc[chrow];

  // staging: 512 threads x 8B covers 4x256 floats
  const int srow = tid >> 7;          // 0..3
  const int scol = (tid & 127) * 2;   // 0..254 even

  __shared__ float h_lds[4][HDIM];
  __shared__ float pre_lds[4][65];    // [batch][ghrow], stride 65

  float acc[4];  // acc[b]

  // prologue: acc = Wx . x[0]
  {
    const float* xb = x + (size_t)b0 * IDIM;
#pragma unroll
    for (int b = 0; b < 4; ++b) acc[b] = 0.f;
#pragma unroll
    for (int j = 0; j < 8; ++j)
#pragma unroll
      for (int b = 0; b < 4; ++b) {
        float4 v = *(const float4*)(xb + b * IDIM + col8[j]);
        acc[b] += wx[4*j+0]*v.x + wx[4*j+1]*v.y + wx[4*j+2]*v.z + wx[4*j+3]*v.w;
      }
  }

  float creg = 0.f, hreg = 0.f;

  for (int t = 0; t < S_LEN; ++t) {
    // --- 1. poll 16 producer flags (tiny traffic) ---
    if (tid < 16) {
      const unsigned tgt = (unsigned)t;
      long cnt = 0;
      while (__hip_atomic_load(&flags[(bg * 16 + tid) * 16], __ATOMIC_RELAXED,
                               __HIP_MEMORY_SCOPE_AGENT) < tgt) {
        if (++cnt > 50000000L) break;  // terminating beats deadlock
      }
    }
    __syncthreads();  // B1

    // --- 2. stage h_prev once: 512 x 8B bypass loads ---
    {
      const float* src = hslot + (size_t)((t & 1) ^ 1) * BATCH * HDIM
                       + (size_t)(b0 + srow) * HDIM + scol;
      unsigned long long u = __hip_atomic_load(
          (const unsigned long long*)src, __ATOMIC_RELAXED,
          __HIP_MEMORY_SCOPE_AGENT);
      h_lds[srow][scol]     = __uint_as_float((unsigned)u);
      h_lds[srow][scol + 1] = __uint_as_float((unsigned)(u >> 32));
    }
    __syncthreads();  // B2

    // --- 3. matvec: acc[b] += Wh_row . h[b]  (conflict-free rotated reads) ---
#pragma unroll
    for (int j = 0; j < 8; ++j)
#pragma unroll
      for (int b = 0; b < 4; ++b) {
        const float4 v = *(const float4*)&h_lds[b][col8[j]];
        acc[b] += wh[4*j+0]*v.x + wh[4*j+1]*v.y + wh[4*j+2]*v.z + wh[4*j+3]*v.w;
      }

    // --- 4. reduce over 8 ks-lanes: scatter xor1,xor2 then butterfly xor4 ---
    float s;
    {
      float a2[2];
      { const int bit = ks & 1;
#pragma unroll
        for (int j = 0; j < 2; ++j) {
          float keep = bit ? acc[2*j+1] : acc[2*j];
          float send = bit ? acc[2*j]   : acc[2*j+1];
          a2[j] = keep + __shfl_xor(send, 1);
        } }
      { const int bit = (ks >> 1) & 1;
        float keep = bit ? a2[1] : a2[0];
        float send = bit ? a2[0] : a2[1];
        s = keep + __shfl_xor(send, 2);
      }
      s += __shfl_xor(s, 4);  // combine the two k-halves
    }
    if (ks < 4) pre_lds[ks][row] = s;  // lane ks holds batch b = ks&3
    __syncthreads();  // B3

    // --- 5. combine gates + publish (tid<64) ---
    if (tid < 64) {
      float gi = pre_lds[cb][0*16 + ch16] + bias_i;
      float gf = pre_lds[cb][1*16 + ch16] + bias_f;
      float go = pre_lds[cb][2*16 + ch16] + bias_o;
      float gc = pre_lds[cb][3*16 + ch16] + bias_c;
      float ig = 1.f / (1.f + expf(-gi));
      float fg = 1.f / (1.f + expf(-gf));
      float og = 1.f / (1.f + expf(-go));
      float cg = tanhf(gc);
      creg = fg * creg + ig * cg;
      hreg = og * tanhf(creg);
      __hip_atomic_store(
          &hslot[(size_t)(t & 1) * BATCH * HDIM + (size_t)(b0 + cb) * HDIM + chrow],
          hreg, __ATOMIC_RELAXED, __HIP_MEMORY_SCOPE_AGENT);
    }
    __syncthreads();  // B4: wave0's publishes drained (vmcnt 0) -> visible
    if (tid == 0) {
      __hip_atomic_store(&flags[bid * 16], (unsigned)(t + 1), __ATOMIC_RELAXED,
                         __HIP_MEMORY_SCOPE_AGENT);
    }

    // ---- off the inter-block critical path ----
    if (tid < 64) {
      out[(size_t)t * BATCH * HDIM + (size_t)(b0 + cb) * HDIM + chrow] = hreg;
    }

    // x-projection for t+1
    {
      const int tn = (t + 1 < S_LEN) ? (t + 1) : (S_LEN - 1);
      const float* xb = x + ((size_t)tn * BATCH + b0) * IDIM;
#pragma unroll
      for (int b = 0; b < 4; ++b) acc[b] = 0.f;
#pragma unroll
      for (int j = 0; j < 8; ++j)
#pragma unroll
        for (int b = 0; b < 4; ++b) {
          float4 v = *(const float4*)(xb + b * IDIM + col8[j]);
          acc[b] += wx[4*j+0]*v.x + wx[4*j+1]*v.y + wx[4*j+2]*v.z + wx[4*j+3]*v.w;
        }
    }
  }

  // final (h, c)
  if (tid < 64) {
    float* oh = out + (size_t)S_LEN * BATCH * HDIM;
    oh[(size_t)(b0 + cb) * HDIM + chrow] = hreg;
    oh[(size_t)BATCH * HDIM + (size_t)(b0 + cb) * HDIM + chrow] = creg;
  }
}

extern "C" void kernel_launch(void* const* d_in, const int* in_sizes, int n_in,
                              void* d_out, int out_size, void* d_ws, size_t ws_size,
                              hipStream_t stream) {
  const float* x   = (const float*)d_in[0];
  const float* Wxi = (const float*)d_in[1];
  const float* Whi = (const float*)d_in[2];
  const float* bxi = (const float*)d_in[3];
  const float* bhi = (const float*)d_in[4];
  const float* Wxf = (const float*)d_in[5];
  const float* Whf = (const float*)d_in[6];
  const float* bxf = (const float*)d_in[7];
  const float* bhf = (const float*)d_in[8];
  const float* Wxo = (const float*)d_in[9];
  const float* Who = (const float*)d_in[10];
  const float* bxo = (const float*)d_in[11];
  const float* bho = (const float*)d_in[12];
  const float* Wxc = (const float*)d_in[13];
  const float* Whc = (const float*)d_in[14];
  const float* bxc = (const float*)d_in[15];
  const float* bhc = (const float*)d_in[16];

  float* out = (float*)d_out;
  float* hslot = (float*)d_ws;
  unsigned int* flags =
      (unsigned int*)((char*)d_ws + (size_t)2 * BATCH * HDIM * sizeof(float));

  // zero h slots (h0 = 0, incl. slot 1 read at t=0) and 512*16 flags;
  // ws re-poisoned 0xAA before every launch -> must re-zero every call.
  hipMemsetAsync(d_ws, 0,
                 (size_t)2 * BATCH * HDIM * sizeof(float) +
                     (size_t)512 * 16 * sizeof(unsigned int),
                 stream);

  lstm_persist<<<dim3(512), dim3(512), 0, stream>>>(
      x, Wxi, Whi, bxi, bhi, Wxf, Whf, bxf, bhf,
      Wxo, Who, bxo, bho, Wxc, Whc, bxc, bhc,
      out, hslot, flags);
}

// Round 8
// 11180.721 us; speedup vs baseline: 1.9064x; 1.9064x over previous
//
#include <hip/hip_runtime.h>
#include <hip/hip_bf16.h>

#define S_LEN 1024
#define BATCH 128
#define HDIM  256
#define IDIM  256

// Persistent fused LSTM, round 8.
// vs round 7 (ONLY change): __launch_bounds__(512, 2). Round 7's (512, 4) was
// interpreted CUDA-style (min 4 blocks/CU) -> VGPR cap 64 -> the 64 pinned
// weight floats/thread spilled to scratch -> 49 GB of spill-reload traffic
// (FETCH_SIZE arithmetic matched 512 blk x 128 KB x 1024 steps exactly).
// (512, 2) -> cap 128 VGPR; natural pressure ~95-110 -> no spill, and
// <=128 VGPR permits 16 waves/CU -> both blocks of a CU stay resident.
// The 2 blocks on a CU are from DIFFERENT batch groups (independent sync
// phases) -> one computes while the other waits on MALL.
//
// Thread tile: 1 gh-row x 32-k (acc[4]); reduce = 3 shfl stages over 8 ks-lanes.
// Rotation (ks+j)&7 spreads matvec ds_read_b128 over all 8 16B-slots.
// Sync protocol (proven r3-r7): relaxed agent-scope atomics (sc0 sc1, no cache
// maintenance); producer h-stores drained by the s_waitcnt vmcnt(0) at
// __syncthreads before tid0 sets its flag; consumers poll 16 tiny flags then
// bulk-read h once. Two-slot ping-pong: writer of slot p at t+2 gated (via
// flags>=t+2) behind all peers' stage-reads of slot p at t+1 -> no overwrite.
//
// grid = 512: bg = bid>>4 (32 batch groups x 4 rows), hsl = bid&15 (16 h-rows).
// block = 512 threads: tid = row*8 + ks (row 0..63 gh-row, ks 0..7 k-slice).

__global__ __launch_bounds__(512, 2) void lstm_persist(
    const float* __restrict__ x,
    const float* __restrict__ Wxi, const float* __restrict__ Whi,
    const float* __restrict__ bxi, const float* __restrict__ bhi,
    const float* __restrict__ Wxf, const float* __restrict__ Whf,
    const float* __restrict__ bxf, const float* __restrict__ bhf,
    const float* __restrict__ Wxo, const float* __restrict__ Who,
    const float* __restrict__ bxo, const float* __restrict__ bho,
    const float* __restrict__ Wxc, const float* __restrict__ Whc,
    const float* __restrict__ bxc, const float* __restrict__ bhc,
    float* __restrict__ out,            // h_seq (S,B,H) then h(B,H) then c(B,H)
    float* __restrict__ hslot,          // ws: 2 * B * H floats, zeroed
    unsigned int* __restrict__ flags)   // ws: 512 * 16 u32 (64B stride), zeroed
{
  const int bid = blockIdx.x;
  const int bg  = bid >> 4;   // 0..31 batch group (4 rows)
  const int hsl = bid & 15;   // 0..15 h-slice (16 h-rows)
  const int tid = threadIdx.x;
  const int row = tid >> 3;   // 0..63 : gh-row = gate*16 + h16
  const int ks  = tid & 7;    // 0..7  : 32-wide k-slice
  const int b0  = bg * 4;

  // rotated k-columns: 8 float4 per thread, slot 4*((ks+j)&7) -> all 32 banks
  int col8[8];
#pragma unroll
  for (int j = 0; j < 8; ++j) col8[j] = ks * 32 + 4 * ((ks + j) & 7);

  // pin weights: 1 gh-row x 32 k (rotated order): 32 Wh + 32 Wx floats
  const int g    = row >> 4;
  const int h16r = row & 15;
  const int hrow = hsl * 16 + h16r;
  const float* Whp = (g == 0) ? Whi : (g == 1) ? Whf : (g == 2) ? Who : Whc;
  const float* Wxp = (g == 0) ? Wxi : (g == 1) ? Wxf : (g == 2) ? Wxo : Wxc;
  float wh[32], wx[32];
#pragma unroll
  for (int j = 0; j < 8; ++j) {
    float4 a = *(const float4*)(Whp + (size_t)hrow * HDIM + col8[j]);
    wh[4*j+0] = a.x; wh[4*j+1] = a.y; wh[4*j+2] = a.z; wh[4*j+3] = a.w;
    float4 c = *(const float4*)(Wxp + (size_t)hrow * IDIM + col8[j]);
    wx[4*j+0] = c.x; wx[4*j+1] = c.y; wx[4*j+2] = c.z; wx[4*j+3] = c.w;
  }

  // combine identity (tid<64): cb = tid>>4 batch row, ch16 = tid&15 h-row
  const int cb   = tid >> 4;
  const int ch16 = tid & 15;
  const int chrow = hsl * 16 + ch16;
  const float bias_i = bxi[chrow] + bhi[chrow];
  const float bias_f = bxf[chrow] + bhf[chrow];
  const float bias_o = bxo[chrow] + bho[chrow];
  const float bias_c = bxc[chrow] + bhc[chrow];

  // staging: 512 threads x 8B covers 4x256 floats
  const int srow = tid >> 7;          // 0..3
  const int scol = (tid & 127) * 2;   // 0..254 even

  __shared__ float h_lds[4][HDIM];
  __shared__ float pre_lds[4][65];    // [batch][ghrow], stride 65

  float acc[4];  // acc[b]

  // prologue: acc = Wx . x[0]
  {
    const float* xb = x + (size_t)b0 * IDIM;
#pragma unroll
    for (int b = 0; b < 4; ++b) acc[b] = 0.f;
#pragma unroll
    for (int j = 0; j < 8; ++j)
#pragma unroll
      for (int b = 0; b < 4; ++b) {
        float4 v = *(const float4*)(xb + b * IDIM + col8[j]);
        acc[b] += wx[4*j+0]*v.x + wx[4*j+1]*v.y + wx[4*j+2]*v.z + wx[4*j+3]*v.w;
      }
  }

  float creg = 0.f, hreg = 0.f;

  for (int t = 0; t < S_LEN; ++t) {
    // --- 1. poll 16 producer flags (tiny traffic) ---
    if (tid < 16) {
      const unsigned tgt = (unsigned)t;
      long cnt = 0;
      while (__hip_atomic_load(&flags[(bg * 16 + tid) * 16], __ATOMIC_RELAXED,
                               __HIP_MEMORY_SCOPE_AGENT) < tgt) {
        if (++cnt > 50000000L) break;  // terminating beats deadlock
      }
    }
    __syncthreads();  // B1

    // --- 2. stage h_prev once: 512 x 8B bypass loads ---
    {
      const float* src = hslot + (size_t)((t & 1) ^ 1) * BATCH * HDIM
                       + (size_t)(b0 + srow) * HDIM + scol;
      unsigned long long u = __hip_atomic_load(
          (const unsigned long long*)src, __ATOMIC_RELAXED,
          __HIP_MEMORY_SCOPE_AGENT);
      h_lds[srow][scol]     = __uint_as_float((unsigned)u);
      h_lds[srow][scol + 1] = __uint_as_float((unsigned)(u >> 32));
    }
    __syncthreads();  // B2

    // --- 3. matvec: acc[b] += Wh_row . h[b]  (conflict-free rotated reads) ---
#pragma unroll
    for (int j = 0; j < 8; ++j)
#pragma unroll
      for (int b = 0; b < 4; ++b) {
        const float4 v = *(const float4*)&h_lds[b][col8[j]];
        acc[b] += wh[4*j+0]*v.x + wh[4*j+1]*v.y + wh[4*j+2]*v.z + wh[4*j+3]*v.w;
      }

    // --- 4. reduce over 8 ks-lanes: scatter xor1,xor2 then butterfly xor4 ---
    float s;
    {
      float a2[2];
      { const int bit = ks & 1;
#pragma unroll
        for (int j = 0; j < 2; ++j) {
          float keep = bit ? acc[2*j+1] : acc[2*j];
          float send = bit ? acc[2*j]   : acc[2*j+1];
          a2[j] = keep + __shfl_xor(send, 1);
        } }
      { const int bit = (ks >> 1) & 1;
        float keep = bit ? a2[1] : a2[0];
        float send = bit ? a2[0] : a2[1];
        s = keep + __shfl_xor(send, 2);
      }
      s += __shfl_xor(s, 4);  // combine the two k-halves
    }
    if (ks < 4) pre_lds[ks][row] = s;  // lane ks holds batch b = ks&3
    __syncthreads();  // B3

    // --- 5. combine gates + publish (tid<64) ---
    if (tid < 64) {
      float gi = pre_lds[cb][0*16 + ch16] + bias_i;
      float gf = pre_lds[cb][1*16 + ch16] + bias_f;
      float go = pre_lds[cb][2*16 + ch16] + bias_o;
      float gc = pre_lds[cb][3*16 + ch16] + bias_c;
      float ig = 1.f / (1.f + expf(-gi));
      float fg = 1.f / (1.f + expf(-gf));
      float og = 1.f / (1.f + expf(-go));
      float cg = tanhf(gc);
      creg = fg * creg + ig * cg;
      hreg = og * tanhf(creg);
      __hip_atomic_store(
          &hslot[(size_t)(t & 1) * BATCH * HDIM + (size_t)(b0 + cb) * HDIM + chrow],
          hreg, __ATOMIC_RELAXED, __HIP_MEMORY_SCOPE_AGENT);
    }
    __syncthreads();  // B4: wave0's publishes drained (vmcnt 0) -> visible
    if (tid == 0) {
      __hip_atomic_store(&flags[bid * 16], (unsigned)(t + 1), __ATOMIC_RELAXED,
                         __HIP_MEMORY_SCOPE_AGENT);
    }

    // ---- off the inter-block critical path ----
    if (tid < 64) {
      out[(size_t)t * BATCH * HDIM + (size_t)(b0 + cb) * HDIM + chrow] = hreg;
    }

    // x-projection for t+1
    {
      const int tn = (t + 1 < S_LEN) ? (t + 1) : (S_LEN - 1);
      const float* xb = x + ((size_t)tn * BATCH + b0) * IDIM;
#pragma unroll
      for (int b = 0; b < 4; ++b) acc[b] = 0.f;
#pragma unroll
      for (int j = 0; j < 8; ++j)
#pragma unroll
        for (int b = 0; b < 4; ++b) {
          float4 v = *(const float4*)(xb + b * IDIM + col8[j]);
          acc[b] += wx[4*j+0]*v.x + wx[4*j+1]*v.y + wx[4*j+2]*v.z + wx[4*j+3]*v.w;
        }
    }
  }

  // final (h, c)
  if (tid < 64) {
    float* oh = out + (size_t)S_LEN * BATCH * HDIM;
    oh[(size_t)(b0 + cb) * HDIM + chrow] = hreg;
    oh[(size_t)BATCH * HDIM + (size_t)(b0 + cb) * HDIM + chrow] = creg;
  }
}

extern "C" void kernel_launch(void* const* d_in, const int* in_sizes, int n_in,
                              void* d_out, int out_size, void* d_ws, size_t ws_size,
                              hipStream_t stream) {
  const float* x   = (const float*)d_in[0];
  const float* Wxi = (const float*)d_in[1];
  const float* Whi = (const float*)d_in[2];
  const float* bxi = (const float*)d_in[3];
  const float* bhi = (const float*)d_in[4];
  const float* Wxf = (const float*)d_in[5];
  const float* Whf = (const float*)d_in[6];
  const float* bxf = (const float*)d_in[7];
  const float* bhf = (const float*)d_in[8];
  const float* Wxo = (const float*)d_in[9];
  const float* Who = (const float*)d_in[10];
  const float* bxo = (const float*)d_in[11];
  const float* bho = (const float*)d_in[12];
  const float* Wxc = (const float*)d_in[13];
  const float* Whc = (const float*)d_in[14];
  const float* bxc = (const float*)d_in[15];
  const float* bhc = (const float*)d_in[16];

  float* out = (float*)d_out;
  float* hslot = (float*)d_ws;
  unsigned int* flags =
      (unsigned int*)((char*)d_ws + (size_t)2 * BATCH * HDIM * sizeof(float));

  // zero h slots (h0 = 0, incl. slot 1 read at t=0) and 512*16 flags;
  // ws re-poisoned 0xAA before every launch -> must re-zero every call.
  hipMemsetAsync(d_ws, 0,
                 (size_t)2 * BATCH * HDIM * sizeof(float) +
                     (size_t)512 * 16 * sizeof(unsigned int),
                 stream);

  lstm_persist<<<dim3(512), dim3(512), 0, stream>>>(
      x, Wxi, Whi, bxi, bhi, Wxf, Whf, bxf, bhf,
      Wxo, Who, bxo, bho, Wxc, Whc, bxc, bhc,
      out, hslot, flags);
}

// Round 9
// 8233.123 us; speedup vs baseline: 2.5889x; 1.3580x over previous
//
#include <hip/hip_runtime.h>
#include <hip/hip_bf16.h>

#define S_LEN 1024
#define BATCH 128
#define HDIM  256
#define IDIM  256

// Persistent fused LSTM, round 9 = round 6 base (best: 7.45 ms) with the
// flag protocol replaced by SELF-VALIDATING TAGGED PAIRS, deduplicated:
//  - h exchanged as 8B (tag=t+1 << 32 | f32 h) relaxed agent-scope atomics.
//  - consumer: each of 512 threads polls exactly ITS OWN two pairs until
//    tag >= t; the successful poll IS the data (one MALL round trip replaces
//    flag-propagate + poll-detect + separate bulk read).
//  - producer: combine threads store pairs directly; NO drain barrier, NO
//    flag store (B4 deleted; 2 barriers/step instead of 4).
// Dedup fixes round 4's failure mode (512KB/block/step redundant poll reads
// -> now 8KB/block/retry).
// Lap safety (same argument as r6, tag==flag): writer of slot t&1 at step t
// passed its stage-poll of slot (t&1)^1 with tags >= t, i.e. every peer
// published step t-1, which happens-after that peer's stage reads of slot
// t&1 at step t-1 -> no overwrite of unread data. Tags in a slot can never
// exceed the consumer's expected t (producer can't reach t+1's publish until
// this consumer publishes t). tag>=t therefore means tag==t: exact.
//
// grid = 256 (1 block/CU; co-residency proven irrelevant in r7/r8 - groups
// are latency-bound, not CU-throughput-bound).
// bg = bid&31 (4 batch rows), hs = bid>>5 (32 h-rows); group members differ
// by stride 32 -> same bid%8 -> likely same XCD (locality only).
// block = 512: tid = hh*16 + kq (hh 0..31 row-group of 4, kq 0..15 k-slice).

__global__ __launch_bounds__(512) void lstm_persist(
    const float* __restrict__ x,
    const float* __restrict__ Wxi, const float* __restrict__ Whi,
    const float* __restrict__ bxi, const float* __restrict__ bhi,
    const float* __restrict__ Wxf, const float* __restrict__ Whf,
    const float* __restrict__ bxf, const float* __restrict__ bhf,
    const float* __restrict__ Wxo, const float* __restrict__ Who,
    const float* __restrict__ bxo, const float* __restrict__ bho,
    const float* __restrict__ Wxc, const float* __restrict__ Whc,
    const float* __restrict__ bxc, const float* __restrict__ bhc,
    float* __restrict__ out,                 // h_seq (S,B,H), h(B,H), c(B,H)
    unsigned long long* __restrict__ hpair)  // ws: 2*B*H pairs (8B), zeroed
{
  const int bid = blockIdx.x;
  const int bg  = bid & 31;
  const int hs  = bid >> 5;
  const int tid = threadIdx.x;
  const int hh  = tid >> 4;   // 0..31 : group of 4 gh-rows
  const int kq  = tid & 15;   // 0..15 : 16-wide k-slice
  const int b0  = bg * 4;

  // rotated k-columns (2-way banks on ds_read_b128 = free per m136)
  int col4[4];
#pragma unroll
  for (int j = 0; j < 4; ++j) col4[j] = kq * 16 + 4 * (((kq >> 1) + j) & 3);

  // pin weights: 4 rows x 16 k (rotated order) for Wh and Wx = 128 VGPRs
  float wh[4][16], wx[4][16];
#pragma unroll
  for (int r = 0; r < 4; ++r) {
    const int ghrow = hh * 4 + r;          // 0..127 = g*32 + hl
    const int g     = ghrow >> 5;
    const int hrow  = hs * 32 + (ghrow & 31);
    const float* Whp = (g == 0) ? Whi : (g == 1) ? Whf : (g == 2) ? Who : Whc;
    const float* Wxp = (g == 0) ? Wxi : (g == 1) ? Wxf : (g == 2) ? Wxo : Wxc;
#pragma unroll
    for (int j = 0; j < 4; ++j) {
      float4 a = *(const float4*)(Whp + (size_t)hrow * HDIM + col4[j]);
      wh[r][4*j+0] = a.x; wh[r][4*j+1] = a.y; wh[r][4*j+2] = a.z; wh[r][4*j+3] = a.w;
      float4 c = *(const float4*)(Wxp + (size_t)hrow * IDIM + col4[j]);
      wx[r][4*j+0] = c.x; wx[r][4*j+1] = c.y; wx[r][4*j+2] = c.z; wx[r][4*j+3] = c.w;
    }
  }

  // combine-thread identity (tid<128)
  const int cb  = tid >> 5;
  const int ch2 = tid & 31;
  const int chrow = hs * 32 + ch2;
  const float bias_i = bxi[chrow] + bhi[chrow];
  const float bias_f = bxf[chrow] + bhf[chrow];
  const float bias_o = bxo[chrow] + bho[chrow];
  const float bias_c = bxc[chrow] + bhc[chrow];

  // staging/poll assignment: thread owns pairs (srow, scol) and (srow, scol+1)
  const int srow = tid >> 7;          // 0..3
  const int scol = (tid & 127) * 2;   // 0..254 even

  __shared__ float h_lds[4][HDIM];
  __shared__ float pre_lds[4][129];   // +1 word stride: spreads b over banks

  float acc[16];  // acc[b + 4*r]

  // prologue: acc = Wx . x[0]
  {
    const float* xb = x + (size_t)b0 * IDIM;
#pragma unroll
    for (int i = 0; i < 16; ++i) acc[i] = 0.f;
#pragma unroll
    for (int j = 0; j < 4; ++j)
#pragma unroll
      for (int b = 0; b < 4; ++b) {
        float4 v = *(const float4*)(xb + b * IDIM + col4[j]);
#pragma unroll
        for (int r = 0; r < 4; ++r)
          acc[b + 4*r] += wx[r][4*j+0]*v.x + wx[r][4*j+1]*v.y
                        + wx[r][4*j+2]*v.z + wx[r][4*j+3]*v.w;
      }
  }

  float creg = 0.f, hreg = 0.f;

  for (int t = 0; t < S_LEN; ++t) {
    // --- 1. poll-stage: each thread spins on ITS two tagged pairs ---
    {
      const unsigned long long* p0 = hpair
          + (size_t)((t & 1) ^ 1) * BATCH * HDIM
          + (size_t)(b0 + srow) * HDIM + scol;
      const unsigned tg = (unsigned)t;
      unsigned long long u0, u1;
      long cnt = 0;
      for (;;) {
        u0 = __hip_atomic_load(p0,     __ATOMIC_RELAXED, __HIP_MEMORY_SCOPE_AGENT);
        u1 = __hip_atomic_load(p0 + 1, __ATOMIC_RELAXED, __HIP_MEMORY_SCOPE_AGENT);
        if (((unsigned)(u0 >> 32) >= tg) & ((unsigned)(u1 >> 32) >= tg)) break;
        if (++cnt > 20000000L) break;  // terminating beats deadlock
      }
      h_lds[srow][scol]     = __uint_as_float((unsigned)u0);
      h_lds[srow][scol + 1] = __uint_as_float((unsigned)u1);
    }
    __syncthreads();  // B2: h_lds ready

    // --- 2. register-tiled matvec: acc += Wh . h ---
#pragma unroll
    for (int j = 0; j < 4; ++j)
#pragma unroll
      for (int b = 0; b < 4; ++b) {
        const float4 v = *(const float4*)&h_lds[b][col4[j]];
#pragma unroll
        for (int r = 0; r < 4; ++r)
          acc[b + 4*r] += wh[r][4*j+0]*v.x + wh[r][4*j+1]*v.y
                        + wh[r][4*j+2]*v.z + wh[r][4*j+3]*v.w;
      }

    // --- 3. reduce-scatter over 16 kq-lanes (15 shfl) ---
    float s;
    {
      float a8[8];
      { const int bit = kq & 1;
#pragma unroll
        for (int j = 0; j < 8; ++j) {
          float keep = bit ? acc[2*j+1] : acc[2*j];
          float send = bit ? acc[2*j]   : acc[2*j+1];
          a8[j] = keep + __shfl_xor(send, 1);
        } }
      float a4[4];
      { const int bit = (kq >> 1) & 1;
#pragma unroll
        for (int j = 0; j < 4; ++j) {
          float keep = bit ? a8[2*j+1] : a8[2*j];
          float send = bit ? a8[2*j]   : a8[2*j+1];
          a4[j] = keep + __shfl_xor(send, 2);
        } }
      float a2[2];
      { const int bit = (kq >> 2) & 1;
#pragma unroll
        for (int j = 0; j < 2; ++j) {
          float keep = bit ? a4[2*j+1] : a4[2*j];
          float send = bit ? a4[2*j]   : a4[2*j+1];
          a2[j] = keep + __shfl_xor(send, 4);
        } }
      { const int bit = (kq >> 3) & 1;
        float keep = bit ? a2[1] : a2[0];
        float send = bit ? a2[0] : a2[1];
        s = keep + __shfl_xor(send, 8);
      }
    }
    pre_lds[kq & 3][hh * 4 + (kq >> 2)] = s;
    __syncthreads();  // B3: pre_lds ready (also fences h_lds reuse next iter)

    // --- 4. combine gates + publish tagged pair (tid<128) ---
    if (tid < 128) {
      float gi = pre_lds[cb][0*32 + ch2] + bias_i;
      float gf = pre_lds[cb][1*32 + ch2] + bias_f;
      float go = pre_lds[cb][2*32 + ch2] + bias_o;
      float gc = pre_lds[cb][3*32 + ch2] + bias_c;
      float ig = 1.f / (1.f + expf(-gi));
      float fg = 1.f / (1.f + expf(-gf));
      float og = 1.f / (1.f + expf(-go));
      float cg = tanhf(gc);
      creg = fg * creg + ig * cg;
      hreg = og * tanhf(creg);
      const int bgl = b0 + cb;
      const unsigned long long u =
          ((unsigned long long)(unsigned)(t + 1) << 32) |
          (unsigned long long)__float_as_uint(hreg);
      __hip_atomic_store(
          &hpair[(size_t)(t & 1) * BATCH * HDIM + (size_t)bgl * HDIM + chrow],
          u, __ATOMIC_RELAXED, __HIP_MEMORY_SCOPE_AGENT);
      out[(size_t)t * BATCH * HDIM + (size_t)bgl * HDIM + chrow] = hreg;
    }
    // no barrier: pairs are self-validating; next stage-poll spins until
    // tags arrive. h_lds/pre_lds hazards are covered by B2/B3 (see header).

    // --- 5. x-projection for t+1 (overlaps pair propagation) ---
    {
      const int tn = (t + 1 < S_LEN) ? (t + 1) : (S_LEN - 1);
      const float* xb = x + ((size_t)tn * BATCH + b0) * IDIM;
#pragma unroll
      for (int i = 0; i < 16; ++i) acc[i] = 0.f;
#pragma unroll
      for (int j = 0; j < 4; ++j)
#pragma unroll
        for (int b = 0; b < 4; ++b) {
          float4 v = *(const float4*)(xb + b * IDIM + col4[j]);
#pragma unroll
          for (int r = 0; r < 4; ++r)
            acc[b + 4*r] += wx[r][4*j+0]*v.x + wx[r][4*j+1]*v.y
                          + wx[r][4*j+2]*v.z + wx[r][4*j+3]*v.w;
        }
    }
  }

  // final (h, c)
  if (tid < 128) {
    float* oh = out + (size_t)S_LEN * BATCH * HDIM;
    const int bgl = b0 + cb;
    oh[(size_t)bgl * HDIM + chrow] = hreg;
    oh[(size_t)BATCH * HDIM + (size_t)bgl * HDIM + chrow] = creg;
  }
}

extern "C" void kernel_launch(void* const* d_in, const int* in_sizes, int n_in,
                              void* d_out, int out_size, void* d_ws, size_t ws_size,
                              hipStream_t stream) {
  const float* x   = (const float*)d_in[0];
  const float* Wxi = (const float*)d_in[1];
  const float* Whi = (const float*)d_in[2];
  const float* bxi = (const float*)d_in[3];
  const float* bhi = (const float*)d_in[4];
  const float* Wxf = (const float*)d_in[5];
  const float* Whf = (const float*)d_in[6];
  const float* bxf = (const float*)d_in[7];
  const float* bhf = (const float*)d_in[8];
  const float* Wxo = (const float*)d_in[9];
  const float* Who = (const float*)d_in[10];
  const float* bxo = (const float*)d_in[11];
  const float* bho = (const float*)d_in[12];
  const float* Wxc = (const float*)d_in[13];
  const float* Whc = (const float*)d_in[14];
  const float* bxc = (const float*)d_in[15];
  const float* bhc = (const float*)d_in[16];

  float* out = (float*)d_out;
  unsigned long long* hpair = (unsigned long long*)d_ws;

  // zero pair slots: h0 = 0, tags = 0 (t=0 poll passes immediately).
  // ws re-poisoned 0xAA before every launch -> must re-zero every call.
  hipMemsetAsync(d_ws, 0, (size_t)2 * BATCH * HDIM * sizeof(unsigned long long),
                 stream);

  lstm_persist<<<dim3(256), dim3(512), 0, stream>>>(
      x, Wxi, Whi, bxi, bhi, Wxf, Whf, bxf, bhf,
      Wxo, Who, bxo, bho, Wxc, Whc, bxc, bhc,
      out, hpair);
}